// Round 1
// baseline (426.806 us; speedup 1.0000x reference)
//
#include <hip/hip_runtime.h>

// VectorQuantizer on MI355X — replicate numpy-fp32 rounding in the distance,
// so argmin matches the np reference's grid-quantized distances exactly.
// x: (32,256,32,32) fp32, codebook: (1024,256) fp32.
// Outputs concat: quantized (8388608 f32), vq_loss (1 f32), indices (32768 as f32).
//
// v2: LDS-throughput was the bottleneck (79 B/cyc/CU ~= ds_read_b128 ceiling).
//  - 4m x 8k register tile (TK=128): 48 B LDS per 32 FMA (was 32 B per 16).
//  - LDS exactly 80 KB (zT 64K + eT 16K, epilogue arrays alias eT) -> 2 blocks/CU.
//  - Ts (row norms) in registers via wave-redundant compute + shuffle.
//  - e-staging kk = t>>1: transpose stores are 2-way (free), was 4-way.
//  - e-tile prefetched to regs during compute (issue-early / write-late).
//  - Per-output arithmetic bit-identical to v1 (chunk-32 fp32 fma chains,
//    double chunk-sum in ascending dc order, same epilogue rounding).

#define NUM_K 1024
#define DIM   256
#define HW    1024          // H*W
#define N_TOT 32768         // B*H*W
#define TM    64            // n-tile per block
#define TK    128           // k-tile
#define DB    32            // d-chunk staged per inner pass (numpy chunk size)
#define NKT   (NUM_K / TK)  // 8
#define NDC   (DIM / DB)    // 8
#define LOSS_OFF 8388608
#define IDX_OFF  8388609

// numpy pairwise sum of squares over 256 elements, exact numpy order.
__device__ __forceinline__ float np_sumsq_256(const float* p, int stride) {
    float s[2];
    #pragma unroll
    for (int h = 0; h < 2; ++h) {
        const float* base = p + h * 128 * stride;
        float r[8];
        #pragma unroll
        for (int j = 0; j < 8; ++j) {
            float v = base[j * stride];
            r[j] = __fmul_rn(v, v);
        }
        for (int i = 8; i < 128; i += 8) {
            #pragma unroll
            for (int j = 0; j < 8; ++j) {
                float v = base[(i + j) * stride];
                r[j] = __fadd_rn(r[j], __fmul_rn(v, v));
            }
        }
        s[h] = __fadd_rn(__fadd_rn(__fadd_rn(r[0], r[1]), __fadd_rn(r[2], r[3])),
                         __fadd_rn(__fadd_rn(r[4], r[5]), __fadd_rn(r[6], r[7])));
    }
    return __fadd_rn(s[0], s[1]);
}

__global__ __launch_bounds__(256) void u2_kernel(const float* __restrict__ cb,
                                                 float* __restrict__ u2) {
    int k = blockIdx.x * 256 + threadIdx.x;     // 4 blocks x 256
    u2[k] = np_sumsq_256(cb + (size_t)k * DIM, 1);
}

__global__ __launch_bounds__(256, 2) void vq_main(const float* __restrict__ x,
                                                  const float* __restrict__ cb,
                                                  const float* __restrict__ u2,
                                                  float* __restrict__ out) {
    // Exactly 80 KB: two blocks fill the 160 KB CU LDS.
    __shared__ __align__(16) unsigned char smem[81920];
    float (*zT)[TM] = (float (*)[TM])smem;                    // [256][64]  64 KB
    float (*eT)[TK] = (float (*)[TK])(smem + 65536);          // [32][128]  16 KB
    // Post-K-loop aliases into the eT region (barrier-separated):
    float* red_v   = (float*)(smem + 65536);                  // [4][64]
    int*   red_k   = (int*)  (smem + 65536 + 1024);           // [4][64]
    int*   bestk_s = (int*)  (smem + 65536 + 2048);           // [64]
    float* wsum    = (float*)(smem + 65536 + 2304);           // [4]

    const int t  = threadIdx.x;
    const int g  = blockIdx.x;          // 512 blocks
    const int n0 = g * TM;
    const int b  = n0 >> 10;            // /1024
    const int r0 = n0 & (HW - 1);
    const size_t xbase = (size_t)b * (DIM * HW) + r0;

    // ---- stage zT[d][m] = x_flat[xbase + d*1024 + m] (coalesced float4) ----
    {
        const int f4 = (t & 15) * 4;
        const int dr = t >> 4;
        #pragma unroll
        for (int it = 0; it < 16; ++it) {
            int d = it * 16 + dr;
            float4 v = *(const float4*)(x + xbase + (size_t)d * HW + f4);
            *(float4*)&zT[d][f4] = v;
        }
    }

    // ---- prefetch first e-tile (kt=0,dc=0) into regs: row skk, 16 floats ----
    const int skk = t >> 1;             // 0..127 (k within tile)
    const int sd0 = (t & 1) * 16;       // 0 or 16 (d within chunk)
    float4 s0, s1, s2, s3;
    {
        const float* src = cb + (size_t)skk * DIM + sd0;
        s0 = *(const float4*)(src + 0);
        s1 = *(const float4*)(src + 4);
        s2 = *(const float4*)(src + 8);
        s3 = *(const float4*)(src + 12);
    }

    __syncthreads();

    // ---- numpy-order ||z||^2: each wave computes all 64 redundantly,
    // then each thread pulls its 4 via shuffle (no LDS slot needed) ----
    float myTs = np_sumsq_256(&zT[0][t & 63], TM);
    const int tm4 = (t & 15) * 4;       // 4 m's per thread
    const int tk8 = (t >> 4) * 8;       // 8 k's (within k-tile) per thread
    float Tsr[4];
    #pragma unroll
    for (int i = 0; i < 4; ++i) Tsr[i] = __shfl(myTs, tm4 + i, 64);

    float best_v[4] = {3.4e38f, 3.4e38f, 3.4e38f, 3.4e38f};
    int   best_k[4] = {0, 0, 0, 0};

    for (int kt = 0; kt < NKT; ++kt) {
        const int k0 = kt * TK;
        double accd[4][8];
        #pragma unroll
        for (int i = 0; i < 4; ++i)
            #pragma unroll
            for (int j = 0; j < 8; ++j) accd[i][j] = 0.0;

        for (int dc = 0; dc < NDC; ++dc) {
            __syncthreads();            // prior dc's eT readers are done
            // transpose-store staged regs: eT[d][k] = cb[k0+k][d0+d]
            // (kk = t>>1 -> 2 lanes/bank on each store: conflict-free)
            eT[sd0 +  0][skk] = s0.x; eT[sd0 +  1][skk] = s0.y;
            eT[sd0 +  2][skk] = s0.z; eT[sd0 +  3][skk] = s0.w;
            eT[sd0 +  4][skk] = s1.x; eT[sd0 +  5][skk] = s1.y;
            eT[sd0 +  6][skk] = s1.z; eT[sd0 +  7][skk] = s1.w;
            eT[sd0 +  8][skk] = s2.x; eT[sd0 +  9][skk] = s2.y;
            eT[sd0 + 10][skk] = s2.z; eT[sd0 + 11][skk] = s2.w;
            eT[sd0 + 12][skk] = s3.x; eT[sd0 + 13][skk] = s3.y;
            eT[sd0 + 14][skk] = s3.z; eT[sd0 + 15][skk] = s3.w;
            __syncthreads();

            // prefetch next e-tile into regs; lands under this dc's FMAs
            {
                int it = kt * NDC + dc + 1;
                if (it < NKT * NDC) {
                    int nk0 = (it >> 3) * TK;
                    int nd0 = (it & 7) * DB;
                    const float* src = cb + (size_t)(nk0 + skk) * DIM + nd0 + sd0;
                    s0 = *(const float4*)(src + 0);
                    s1 = *(const float4*)(src + 4);
                    s2 = *(const float4*)(src + 8);
                    s3 = *(const float4*)(src + 12);
                }
            }

            const int d0 = dc * DB;
            float af[4][8];
            #pragma unroll
            for (int d = 0; d < DB; ++d) {
                float4 zv = *(const float4*)&zT[d0 + d][tm4];
                float4 e0 = *(const float4*)&eT[d][tk8];
                float4 e1 = *(const float4*)&eT[d][tk8 + 4];
                float za[4] = {zv.x, zv.y, zv.z, zv.w};
                float ea[8] = {e0.x, e0.y, e0.z, e0.w, e1.x, e1.y, e1.z, e1.w};
                #pragma unroll
                for (int i = 0; i < 4; ++i)
                    #pragma unroll
                    for (int j = 0; j < 8; ++j)
                        af[i][j] = (d == 0) ? __fmul_rn(za[i], ea[j])      // fma(a,b,0)==a*b
                                            : fmaf(za[i], ea[j], af[i][j]);
            }
            #pragma unroll
            for (int i = 0; i < 4; ++i)
                #pragma unroll
                for (int j = 0; j < 8; ++j) accd[i][j] += (double)af[i][j];
        }

        // ---- replicate numpy: d = fl32( fl32(T_n + U_k) - 2*fl32(dot) ) ----
        float4 u0 = *(const float4*)(u2 + k0 + tk8);
        float4 u1 = *(const float4*)(u2 + k0 + tk8 + 4);
        float ua[8] = {u0.x, u0.y, u0.z, u0.w, u1.x, u1.y, u1.z, u1.w};
        #pragma unroll
        for (int j = 0; j < 8; ++j) {
            const int kk = k0 + tk8 + j;
            #pragma unroll
            for (int i = 0; i < 4; ++i) {
                float m32 = (float)accd[i][j];              // fl32(dot)
                float c   = __fmul_rn(2.0f, m32);           // exact
                float t1  = __fadd_rn(Tsr[i], ua[j]);       // fl32(T+U)
                float d32 = __fsub_rn(t1, c);               // fl32(t1-c)
                // strict < keeps the earliest k (ks ascend within a thread)
                if (d32 < best_v[i]) { best_v[i] = d32; best_k[i] = kk; }
            }
        }
    }

    __syncthreads();   // all eT reads done -> alias region is now safe

    // ---- argmin reduction across the 4 tk-subgroups within the wave ----
    #pragma unroll
    for (int i = 0; i < 4; ++i) {
        float v = best_v[i]; int k = best_k[i];
        #pragma unroll
        for (int off = 16; off < 64; off <<= 1) {
            float ov = __shfl_xor(v, off, 64);
            int   ok = __shfl_xor(k, off, 64);
            if (ov < v || (ov == v && ok < k)) { v = ov; k = ok; }
        }
        best_v[i] = v; best_k[i] = k;
    }
    const int wv = t >> 6;              // wave id 0..3
    if ((t & 63) < 16) {
        #pragma unroll
        for (int i = 0; i < 4; ++i) {
            red_v[wv * TM + tm4 + i] = best_v[i];
            red_k[wv * TM + tm4 + i] = best_k[i];
        }
    }
    __syncthreads();
    if (t < TM) {
        float bv = red_v[t]; int bk = red_k[t];
        #pragma unroll
        for (int q = 1; q < 4; ++q) {
            float v = red_v[q * TM + t]; int k = red_k[q * TM + t];
            if (v < bv || (v == bv && k < bk)) { bv = v; bk = k; }
        }
        bestk_s[t] = bk;
        out[IDX_OFF + n0 + t] = (float)bk;   // indices as float
    }
    __syncthreads();

    // ---- epilogue: quantized output + fused loss ----
    float lsum = 0.f;
    {
        const int m = t & 63;
        const int kq = bestk_s[m];
        const float* crow = cb + (size_t)kq * DIM;
        for (int c = (t >> 6); c < DIM; c += 4) {
            float qv = crow[c];
            float xv = zT[c][m];
            float d  = qv - xv;
            lsum = fmaf(d, d, lsum);
            out[xbase + (size_t)c * HW + m] = qv;
        }
    }
    #pragma unroll
    for (int off = 32; off > 0; off >>= 1) lsum += __shfl_down(lsum, off, 64);
    if ((t & 63) == 0) wsum[wv] = lsum;
    __syncthreads();
    if (t == 0) {
        float s = (wsum[0] + wsum[1]) + (wsum[2] + wsum[3]);
        // vq_loss = q_latent + 0.25*e_latent, both equal mean((q-x)^2)
        atomicAdd(out + LOSS_OFF, s * (1.25f / 8388608.0f));
    }
}

extern "C" void kernel_launch(void* const* d_in, const int* in_sizes, int n_in,
                              void* d_out, int out_size, void* d_ws, size_t ws_size,
                              hipStream_t stream) {
    const float* x  = (const float*)d_in[0];
    const float* cb = (const float*)d_in[1];
    float* out = (float*)d_out;
    float* u2  = (float*)d_ws;          // 4 KB scratch (numpy-order ||e||^2)

    // zero the loss slot (atomicAdd target); graph-capture-safe
    hipMemsetAsync(out + LOSS_OFF, 0, sizeof(float), stream);
    u2_kernel<<<NUM_K / 256, 256, 0, stream>>>(cb, u2);
    vq_main<<<N_TOT / TM, 256, 0, stream>>>(x, cb, u2, out);
}

// Round 2
// 423.532 us; speedup vs baseline: 1.0077x; 1.0077x over previous
//
#include <hip/hip_runtime.h>

// VectorQuantizer on MI355X — replicate numpy-fp32 rounding in the distance,
// so argmin matches the np reference's grid-quantized distances exactly.
// x: (32,256,32,32) fp32, codebook: (1024,256) fp32.
// Outputs concat: quantized (8388608 f32), vq_loss (1 f32), indices (32768 as f32).
//
// v3: v2's 4m x 8k tile (1.5 B LDS per FMA) was correct but the allocator
// capped VGPRs at 128 (targeting 4 waves/SIMD) and spilled ~40 regs to
// scratch -> 330 MB of write-through HBM traffic (WRITE_SIZE 357 MB) and a
// 12% regression. LDS caps occupancy at 2 blocks/CU (80 KB each) anyway,
// so pin the allocator to exactly 2 waves/EU via amdgpu_waves_per_eu(2,2):
// budget becomes 256 VGPRs, the ~170 live regs fit, no spill.
//  - 4m x 8k register tile (TK=128): 48 B LDS per 32 FMA.
//  - LDS exactly 80 KB (zT 64K + eT 16K, epilogue arrays alias eT).
//  - Ts (row norms) in registers via wave-redundant compute + shuffle.
//  - e-staging kk = t>>1: transpose stores are 2-way (free).
//  - e-tile prefetched to regs during compute (issue-early / write-late).
//  - Per-output arithmetic bit-identical to v1/v2 (chunk-32 fp32 fma chains,
//    double chunk-sum in ascending dc order, same epilogue rounding).

#define NUM_K 1024
#define DIM   256
#define HW    1024          // H*W
#define N_TOT 32768         // B*H*W
#define TM    64            // n-tile per block
#define TK    128           // k-tile
#define DB    32            // d-chunk staged per inner pass (numpy chunk size)
#define NKT   (NUM_K / TK)  // 8
#define NDC   (DIM / DB)    // 8
#define LOSS_OFF 8388608
#define IDX_OFF  8388609

// numpy pairwise sum of squares over 256 elements, exact numpy order.
__device__ __forceinline__ float np_sumsq_256(const float* p, int stride) {
    float s[2];
    #pragma unroll
    for (int h = 0; h < 2; ++h) {
        const float* base = p + h * 128 * stride;
        float r[8];
        #pragma unroll
        for (int j = 0; j < 8; ++j) {
            float v = base[j * stride];
            r[j] = __fmul_rn(v, v);
        }
        for (int i = 8; i < 128; i += 8) {
            #pragma unroll
            for (int j = 0; j < 8; ++j) {
                float v = base[(i + j) * stride];
                r[j] = __fadd_rn(r[j], __fmul_rn(v, v));
            }
        }
        s[h] = __fadd_rn(__fadd_rn(__fadd_rn(r[0], r[1]), __fadd_rn(r[2], r[3])),
                         __fadd_rn(__fadd_rn(r[4], r[5]), __fadd_rn(r[6], r[7])));
    }
    return __fadd_rn(s[0], s[1]);
}

__global__ __launch_bounds__(256) void u2_kernel(const float* __restrict__ cb,
                                                 float* __restrict__ u2) {
    int k = blockIdx.x * 256 + threadIdx.x;     // 4 blocks x 256
    u2[k] = np_sumsq_256(cb + (size_t)k * DIM, 1);
}

__attribute__((amdgpu_waves_per_eu(2, 2)))
__global__ __launch_bounds__(256) void vq_main(const float* __restrict__ x,
                                               const float* __restrict__ cb,
                                               const float* __restrict__ u2,
                                               float* __restrict__ out) {
    // Exactly 80 KB: two blocks fill the 160 KB CU LDS.
    __shared__ __align__(16) unsigned char smem[81920];
    float (*zT)[TM] = (float (*)[TM])smem;                    // [256][64]  64 KB
    float (*eT)[TK] = (float (*)[TK])(smem + 65536);          // [32][128]  16 KB
    // Post-K-loop aliases into the eT region (barrier-separated):
    float* red_v   = (float*)(smem + 65536);                  // [4][64]
    int*   red_k   = (int*)  (smem + 65536 + 1024);           // [4][64]
    int*   bestk_s = (int*)  (smem + 65536 + 2048);           // [64]
    float* wsum    = (float*)(smem + 65536 + 2304);           // [4]

    const int t  = threadIdx.x;
    const int g  = blockIdx.x;          // 512 blocks
    const int n0 = g * TM;
    const int b  = n0 >> 10;            // /1024
    const int r0 = n0 & (HW - 1);
    const size_t xbase = (size_t)b * (DIM * HW) + r0;

    // ---- stage zT[d][m] = x_flat[xbase + d*1024 + m] (coalesced float4) ----
    {
        const int f4 = (t & 15) * 4;
        const int dr = t >> 4;
        #pragma unroll
        for (int it = 0; it < 16; ++it) {
            int d = it * 16 + dr;
            float4 v = *(const float4*)(x + xbase + (size_t)d * HW + f4);
            *(float4*)&zT[d][f4] = v;
        }
    }

    // ---- prefetch first e-tile (kt=0,dc=0) into regs: row skk, 16 floats ----
    const int skk = t >> 1;             // 0..127 (k within tile)
    const int sd0 = (t & 1) * 16;       // 0 or 16 (d within chunk)
    float4 s0, s1, s2, s3;
    {
        const float* src = cb + (size_t)skk * DIM + sd0;
        s0 = *(const float4*)(src + 0);
        s1 = *(const float4*)(src + 4);
        s2 = *(const float4*)(src + 8);
        s3 = *(const float4*)(src + 12);
    }

    __syncthreads();

    // ---- numpy-order ||z||^2: each wave computes all 64 redundantly,
    // then each thread pulls its 4 via shuffle (no LDS slot needed) ----
    float myTs = np_sumsq_256(&zT[0][t & 63], TM);
    const int tm4 = (t & 15) * 4;       // 4 m's per thread
    const int tk8 = (t >> 4) * 8;       // 8 k's (within k-tile) per thread
    float Tsr[4];
    #pragma unroll
    for (int i = 0; i < 4; ++i) Tsr[i] = __shfl(myTs, tm4 + i, 64);

    float best_v[4] = {3.4e38f, 3.4e38f, 3.4e38f, 3.4e38f};
    int   best_k[4] = {0, 0, 0, 0};

    for (int kt = 0; kt < NKT; ++kt) {
        const int k0 = kt * TK;
        double accd[4][8];
        #pragma unroll
        for (int i = 0; i < 4; ++i)
            #pragma unroll
            for (int j = 0; j < 8; ++j) accd[i][j] = 0.0;

        for (int dc = 0; dc < NDC; ++dc) {
            __syncthreads();            // prior dc's eT readers are done
            // transpose-store staged regs: eT[d][k] = cb[k0+k][d0+d]
            // (kk = t>>1 -> 2 lanes/bank on each store: conflict-free)
            eT[sd0 +  0][skk] = s0.x; eT[sd0 +  1][skk] = s0.y;
            eT[sd0 +  2][skk] = s0.z; eT[sd0 +  3][skk] = s0.w;
            eT[sd0 +  4][skk] = s1.x; eT[sd0 +  5][skk] = s1.y;
            eT[sd0 +  6][skk] = s1.z; eT[sd0 +  7][skk] = s1.w;
            eT[sd0 +  8][skk] = s2.x; eT[sd0 +  9][skk] = s2.y;
            eT[sd0 + 10][skk] = s2.z; eT[sd0 + 11][skk] = s2.w;
            eT[sd0 + 12][skk] = s3.x; eT[sd0 + 13][skk] = s3.y;
            eT[sd0 + 14][skk] = s3.z; eT[sd0 + 15][skk] = s3.w;
            __syncthreads();

            // prefetch next e-tile into regs; lands under this dc's FMAs
            {
                int it = kt * NDC + dc + 1;
                if (it < NKT * NDC) {
                    int nk0 = (it >> 3) * TK;
                    int nd0 = (it & 7) * DB;
                    const float* src = cb + (size_t)(nk0 + skk) * DIM + nd0 + sd0;
                    s0 = *(const float4*)(src + 0);
                    s1 = *(const float4*)(src + 4);
                    s2 = *(const float4*)(src + 8);
                    s3 = *(const float4*)(src + 12);
                }
            }

            const int d0 = dc * DB;
            float af[4][8];
            #pragma unroll
            for (int d = 0; d < DB; ++d) {
                float4 zv = *(const float4*)&zT[d0 + d][tm4];
                float4 e0 = *(const float4*)&eT[d][tk8];
                float4 e1 = *(const float4*)&eT[d][tk8 + 4];
                float za[4] = {zv.x, zv.y, zv.z, zv.w};
                float ea[8] = {e0.x, e0.y, e0.z, e0.w, e1.x, e1.y, e1.z, e1.w};
                #pragma unroll
                for (int i = 0; i < 4; ++i)
                    #pragma unroll
                    for (int j = 0; j < 8; ++j)
                        af[i][j] = (d == 0) ? __fmul_rn(za[i], ea[j])      // fma(a,b,0)==a*b
                                            : fmaf(za[i], ea[j], af[i][j]);
            }
            #pragma unroll
            for (int i = 0; i < 4; ++i)
                #pragma unroll
                for (int j = 0; j < 8; ++j) accd[i][j] += (double)af[i][j];
        }

        // ---- replicate numpy: d = fl32( fl32(T_n + U_k) - 2*fl32(dot) ) ----
        float4 u0 = *(const float4*)(u2 + k0 + tk8);
        float4 u1 = *(const float4*)(u2 + k0 + tk8 + 4);
        float ua[8] = {u0.x, u0.y, u0.z, u0.w, u1.x, u1.y, u1.z, u1.w};
        #pragma unroll
        for (int j = 0; j < 8; ++j) {
            const int kk = k0 + tk8 + j;
            #pragma unroll
            for (int i = 0; i < 4; ++i) {
                float m32 = (float)accd[i][j];              // fl32(dot)
                float c   = __fmul_rn(2.0f, m32);           // exact
                float t1  = __fadd_rn(Tsr[i], ua[j]);       // fl32(T+U)
                float d32 = __fsub_rn(t1, c);               // fl32(t1-c)
                // strict < keeps the earliest k (ks ascend within a thread)
                if (d32 < best_v[i]) { best_v[i] = d32; best_k[i] = kk; }
            }
        }
    }

    __syncthreads();   // all eT reads done -> alias region is now safe

    // ---- argmin reduction across the 4 tk-subgroups within the wave ----
    #pragma unroll
    for (int i = 0; i < 4; ++i) {
        float v = best_v[i]; int k = best_k[i];
        #pragma unroll
        for (int off = 16; off < 64; off <<= 1) {
            float ov = __shfl_xor(v, off, 64);
            int   ok = __shfl_xor(k, off, 64);
            if (ov < v || (ov == v && ok < k)) { v = ov; k = ok; }
        }
        best_v[i] = v; best_k[i] = k;
    }
    const int wv = t >> 6;              // wave id 0..3
    if ((t & 63) < 16) {
        #pragma unroll
        for (int i = 0; i < 4; ++i) {
            red_v[wv * TM + tm4 + i] = best_v[i];
            red_k[wv * TM + tm4 + i] = best_k[i];
        }
    }
    __syncthreads();
    if (t < TM) {
        float bv = red_v[t]; int bk = red_k[t];
        #pragma unroll
        for (int q = 1; q < 4; ++q) {
            float v = red_v[q * TM + t]; int k = red_k[q * TM + t];
            if (v < bv || (v == bv && k < bk)) { bv = v; bk = k; }
        }
        bestk_s[t] = bk;
        out[IDX_OFF + n0 + t] = (float)bk;   // indices as float
    }
    __syncthreads();

    // ---- epilogue: quantized output + fused loss ----
    float lsum = 0.f;
    {
        const int m = t & 63;
        const int kq = bestk_s[m];
        const float* crow = cb + (size_t)kq * DIM;
        for (int c = (t >> 6); c < DIM; c += 4) {
            float qv = crow[c];
            float xv = zT[c][m];
            float d  = qv - xv;
            lsum = fmaf(d, d, lsum);
            out[xbase + (size_t)c * HW + m] = qv;
        }
    }
    #pragma unroll
    for (int off = 32; off > 0; off >>= 1) lsum += __shfl_down(lsum, off, 64);
    if ((t & 63) == 0) wsum[wv] = lsum;
    __syncthreads();
    if (t == 0) {
        float s = (wsum[0] + wsum[1]) + (wsum[2] + wsum[3]);
        // vq_loss = q_latent + 0.25*e_latent, both equal mean((q-x)^2)
        atomicAdd(out + LOSS_OFF, s * (1.25f / 8388608.0f));
    }
}

extern "C" void kernel_launch(void* const* d_in, const int* in_sizes, int n_in,
                              void* d_out, int out_size, void* d_ws, size_t ws_size,
                              hipStream_t stream) {
    const float* x  = (const float*)d_in[0];
    const float* cb = (const float*)d_in[1];
    float* out = (float*)d_out;
    float* u2  = (float*)d_ws;          // 4 KB scratch (numpy-order ||e||^2)

    // zero the loss slot (atomicAdd target); graph-capture-safe
    hipMemsetAsync(out + LOSS_OFF, 0, sizeof(float), stream);
    u2_kernel<<<NUM_K / 256, 256, 0, stream>>>(cb, u2);
    vq_main<<<N_TOT / TM, 256, 0, stream>>>(x, cb, u2, out);
}